// Round 6
// baseline (162.491 us; speedup 1.0000x reference)
//
#include <hip/hip_runtime.h>
#include <math.h>

#define TS 8192               // dg table size (32 KB, L1/L2-resident)
#define NPTS 16384            // N per row
#define NROWS 256             // B
#define CPR 8                 // chunks per row
#define CHUNK 2048            // elements per chunk
#define EPT 8                 // elements per thread (256 thr * 8 = 2048)

// softplus via hardware transcendentals (v_exp_f32 / v_log_f32)
__device__ __forceinline__ float softplus(float x) {
    float ax = fabsf(x);
    return fmaxf(x, 0.0f) + __logf(1.0f + __expf(-ax));
}

// LDS layout offsets (floats) for the staged weights
#define OFF_W1 0            // 32
#define OFF_B1 32           // 32
#define OFF_W2 64           // 2048
#define OFF_B2 2112         // 64
#define OFF_W3 2176         // 4096
#define OFF_B3 6272         // 64
#define OFF_W4 6336         // 2048
#define OFF_B4 8384         // 32
#define OFF_W5 8416         // 32
#define OFF_B5 8448         // 1
#define WTOT   8449

// Kernel 1: tabulate dg(t) = MLP(t) on uniform grid over [0,10].
// (R4 structure, est ~5us: block=512 computes 32 entries; lane&31 = entry,
// lane>>5 = k-half, wave = j-slice; weights in LDS, layer exchange via
// padded hbuf, halves combined via shfl_xor(32).)
__global__ __launch_bounds__(512, 2) void build_table(
    const float* __restrict__ W1, const float* __restrict__ b1,
    const float* __restrict__ W2, const float* __restrict__ b2,
    const float* __restrict__ W3, const float* __restrict__ b3,
    const float* __restrict__ W4, const float* __restrict__ b4,
    const float* __restrict__ W5, const float* __restrict__ b5,
    float* __restrict__ table)
{
    __shared__ float w[WTOT];
    __shared__ float hbuf[32][65];

    const int tid  = threadIdx.x;
    const int lane = tid & 63;
    const int wave = tid >> 6;
    const int half = lane >> 5;
    const int e    = lane & 31;

    {
        float4*       d2 = (float4*)(w + OFF_W2);
        const float4* s2 = (const float4*)W2;
        d2[tid] = s2[tid];
        float4*       d3 = (float4*)(w + OFF_W3);
        const float4* s3 = (const float4*)W3;
        d3[tid] = s3[tid]; d3[512 + tid] = s3[512 + tid];
        float4*       d4 = (float4*)(w + OFF_W4);
        const float4* s4 = (const float4*)W4;
        d4[tid] = s4[tid];
        if (tid < 32) {
            w[OFF_W1 + tid] = W1[tid];
            w[OFF_B1 + tid] = b1[tid];
            w[OFF_B4 + tid] = b4[tid];
            w[OFF_W5 + tid] = W5[tid];
        }
        if (tid < 64) {
            w[OFF_B2 + tid] = b2[tid];
            w[OFF_B3 + tid] = b3[tid];
        }
        if (tid == 0) w[OFF_B5] = b5[0];
    }
    __syncthreads();

    const int   i = blockIdx.x * 32 + e;
    const float t = 10.0f * (float)i / (float)(TS - 1);

    // L1: 1 -> 32
#pragma unroll
    for (int jj = 0; jj < 4; ++jj) {
        int j = wave * 4 + jj;
        float v = softplus(fmaf(t, w[OFF_W1 + j], w[OFF_B1 + j]));
        if (half == 0) hbuf[e][j] = v;
    }
    __syncthreads();

    // L2: 32 -> 64
    {
        float hr[16];
        const float* hp = &hbuf[e][half * 16];
#pragma unroll
        for (int k = 0; k < 16; ++k) hr[k] = hp[k];
        float acc[8];
#pragma unroll
        for (int jj = 0; jj < 8; ++jj) {
            int j = wave * 8 + jj;
            const float* wp = &w[OFF_W2 + j * 32 + half * 16];
            float a = 0.0f;
#pragma unroll
            for (int k = 0; k < 16; ++k) a = fmaf(hr[k], wp[k], a);
            acc[jj] = a;
        }
        __syncthreads();
#pragma unroll
        for (int jj = 0; jj < 8; ++jj) {
            int j = wave * 8 + jj;
            float s = acc[jj] + __shfl_xor(acc[jj], 32, 64);
            float v = softplus(s + w[OFF_B2 + j]);
            if (half == 0) hbuf[e][j] = v;
        }
    }
    __syncthreads();

    // L3: 64 -> 64
    {
        float hr[32];
        const float* hp = &hbuf[e][half * 32];
#pragma unroll
        for (int k = 0; k < 32; ++k) hr[k] = hp[k];
        float acc[8];
#pragma unroll
        for (int jj = 0; jj < 8; ++jj) {
            int j = wave * 8 + jj;
            const float* wp = &w[OFF_W3 + j * 64 + half * 32];
            float a = 0.0f;
#pragma unroll
            for (int k = 0; k < 32; ++k) a = fmaf(hr[k], wp[k], a);
            acc[jj] = a;
        }
        __syncthreads();
#pragma unroll
        for (int jj = 0; jj < 8; ++jj) {
            int j = wave * 8 + jj;
            float s = acc[jj] + __shfl_xor(acc[jj], 32, 64);
            float v = softplus(s + w[OFF_B3 + j]);
            if (half == 0) hbuf[e][j] = v;
        }
    }
    __syncthreads();

    // L4: 64 -> 32
    {
        float hr[32];
        const float* hp = &hbuf[e][half * 32];
#pragma unroll
        for (int k = 0; k < 32; ++k) hr[k] = hp[k];
        float acc[4];
#pragma unroll
        for (int jj = 0; jj < 4; ++jj) {
            int j = wave * 4 + jj;
            const float* wp = &w[OFF_W4 + j * 64 + half * 32];
            float a = 0.0f;
#pragma unroll
            for (int k = 0; k < 32; ++k) a = fmaf(hr[k], wp[k], a);
            acc[jj] = a;
        }
        __syncthreads();
#pragma unroll
        for (int jj = 0; jj < 4; ++jj) {
            int j = wave * 4 + jj;
            float s = acc[jj] + __shfl_xor(acc[jj], 32, 64);
            float v = softplus(s + w[OFF_B4 + j]);
            if (half == 0) hbuf[e][j] = v;
        }
    }
    __syncthreads();

    // L5: 32 -> 1, +1.0
    if (wave == 0) {
        const float* hp = &hbuf[e][half * 16];
        const float* wp = &w[OFF_W5 + half * 16];
        float a = 0.0f;
#pragma unroll
        for (int k = 0; k < 16; ++k) a = fmaf(hp[k], wp[k], a);
        float s = a + __shfl_xor(a, 32, 64);
        float v = softplus(s + w[OFF_B5]) + 1.0f;
        if (half == 0) table[blockIdx.x * 32 + e] = v;
    }
}

__device__ __forceinline__ float dg_lookup(const float* __restrict__ tab, float t) {
    const float scale = (float)(TS - 1) / 10.0f;
    float x = t * scale;
    x = fminf(fmaxf(x, 0.0f), (float)(TS - 1));
    int i = (int)x;
    if (i > TS - 2) i = TS - 2;
    float f = x - (float)i;
    float a = tab[i];
    float b = tab[i + 1];
    return fmaf(b - a, f, a);
}

// Kernel 2: fused scan with decoupled lookback (single pass over t).
// 2048 blocks x 256 threads; block b: chunk = b>>8, row = b&255 -> same-row
// predecessors have IDs lower by >=256 (dispatched earlier; all 2048 blocks
// co-resident at 8 blocks/CU anyway). Each block publishes its chunk total
// as one 64-bit packet (1<<32 | float bits) with device-scope release;
// successors acquire-spin on <=7 predecessors in parallel (one per lane).
// d_ws 0xAA poison != flag 1 -> flags self-initialize each launch.
__global__ __launch_bounds__(256) void scan_fused(
    const float* __restrict__ t,
    const float* __restrict__ table,
    unsigned long long* __restrict__ sf,
    float* __restrict__ out)
{
    const int blk   = blockIdx.x;
    const int chunk = blk >> 8;            // 0..7
    const int row   = blk & (NROWS - 1);   // 0..255
    const float* tr = t + (size_t)row * NPTS;
    float*       gr = out + (size_t)row * NPTS;
    const int tid   = threadIdx.x;
    const int lane  = tid & 63;
    const int wave  = tid >> 6;
    const int base  = chunk * CHUNK + tid * EPT;

    // ---- load 8 t's, compute increments ----
    float tv[EPT];
    const float4* p = (const float4*)(tr + base);
    float4 a4 = p[0], b4 = p[1];
    tv[0] = a4.x; tv[1] = a4.y; tv[2] = a4.z; tv[3] = a4.w;
    tv[4] = b4.x; tv[5] = b4.y; tv[6] = b4.z; tv[7] = b4.w;

    float tprev = __shfl_up(tv[7], 1, 64);
    if (lane == 0)
        tprev = (base == 0) ? tv[0] : tr[base - 1];

    float inc[EPT];
    float s  = 0.0f;
    float tp = tprev;
    float dp = dg_lookup(table, tprev);
#pragma unroll
    for (int q = 0; q < EPT; ++q) {
        float dc = dg_lookup(table, tv[q]);
        inc[q] = 0.5f * (dc + dp) * (tv[q] - tp);
        s += inc[q];
        tp = tv[q];
        dp = dc;
    }

    // ---- wave-level inclusive scan of per-thread totals ----
    float v = s;
#pragma unroll
    for (int d = 1; d < 64; d <<= 1) {
        float u = __shfl_up(v, d, 64);
        if (lane >= d) v += u;
    }

    __shared__ float wsum[4];
    __shared__ float offsh;
    if (lane == 63) wsum[wave] = v;
    __syncthreads();

    // ---- publish own chunk total ASAP (tid 0) ----
    if (tid == 0) {
        float total = wsum[0] + wsum[1] + wsum[2] + wsum[3];
        unsigned long long pkt =
            (1ull << 32) | (unsigned long long)__float_as_uint(total);
        __hip_atomic_store(&sf[blk], pkt, __ATOMIC_RELEASE,
                           __HIP_MEMORY_SCOPE_AGENT);
    }

    // ---- lookback: wave 0, lane j spins on predecessor chunk j ----
    if (wave == 0) {
        float off = 0.0f;
        if (lane < chunk) {
            const unsigned long long* pp = &sf[lane * NROWS + row];
            unsigned long long pkt;
            while (((pkt = __hip_atomic_load(pp, __ATOMIC_ACQUIRE,
                                             __HIP_MEMORY_SCOPE_AGENT)) >> 32)
                   != 1ull)
                __builtin_amdgcn_s_sleep(1);
            off = __uint_as_float((unsigned)pkt);
        }
        // fold lanes 0..7 (lanes >= chunk hold 0)
#pragma unroll
        for (int d = 1; d < 8; d <<= 1) off += __shfl_xor(off, d, 8);
        if (lane == 0) offsh = off;
    }
    __syncthreads();

    // ---- emit ----
    float woff = offsh;
#pragma unroll
    for (int w = 0; w < 3; ++w)
        woff += (w < wave) ? wsum[w] : 0.0f;

    float running = woff + (v - s);   // exclusive prefix for this thread
    float4* g4 = (float4*)(gr + base);
    float4 o0, o1;
    running += inc[0]; o0.x = running;
    running += inc[1]; o0.y = running;
    running += inc[2]; o0.z = running;
    running += inc[3]; o0.w = running;
    running += inc[4]; o1.x = running;
    running += inc[5]; o1.y = running;
    running += inc[6]; o1.z = running;
    running += inc[7]; o1.w = running;
    g4[0] = o0; g4[1] = o1;
}

extern "C" void kernel_launch(void* const* d_in, const int* in_sizes, int n_in,
                              void* d_out, int out_size, void* d_ws, size_t ws_size,
                              hipStream_t stream)
{
    const float* t  = (const float*)d_in[0];
    const float* W1 = (const float*)d_in[1];
    const float* b1 = (const float*)d_in[2];
    const float* W2 = (const float*)d_in[3];
    const float* b2 = (const float*)d_in[4];
    const float* W3 = (const float*)d_in[5];
    const float* b3 = (const float*)d_in[6];
    const float* W4 = (const float*)d_in[7];
    const float* b4 = (const float*)d_in[8];
    const float* W5 = (const float*)d_in[9];
    const float* b5 = (const float*)d_in[10];
    float* table = (float*)d_ws;                                  // 32 KB
    unsigned long long* sf = (unsigned long long*)((char*)d_ws + 65536);
    float* out   = (float*)d_out;

    build_table<<<TS / 32, 512, 0, stream>>>(W1, b1, W2, b2, W3, b3, W4, b4, W5, b5, table);
    scan_fused<<<NROWS * CPR, 256, 0, stream>>>(t, table, sf, out);
}

// Round 7
// 95.765 us; speedup vs baseline: 1.6968x; 1.6968x over previous
//
#include <hip/hip_runtime.h>
#include <math.h>

#define TS 4096               // dg table size (16 KB)
#define NPTS 16384            // N per row
#define NROWS 256             // B
#define PAD 17                // per-thread G-slice stride (16 entries + 1 pad)

// softplus via hardware transcendentals (v_exp_f32 / v_log_f32)
__device__ __forceinline__ float softplus(float x) {
    float ax = fabsf(x);
    return fmaxf(x, 0.0f) + __logf(1.0f + __expf(-ax));
}

// LDS layout offsets (floats) for the staged weights
#define OFF_W1 0            // 32
#define OFF_B1 32           // 32
#define OFF_W2 64           // 2048
#define OFF_B2 2112         // 64
#define OFF_W3 2176         // 4096
#define OFF_B3 6272         // 64
#define OFF_W4 6336         // 2048
#define OFF_B4 8384         // 32
#define OFF_W5 8416         // 32
#define OFF_B5 8448         // 1
#define WTOT   8449

// Kernel 1: tabulate dg(t) = MLP(t) on uniform grid over [0,10].
// (R4-proven structure: block=512 computes 32 entries; lane&31 = entry,
// lane>>5 = k-half, wave = j-slice; weights in LDS, layer exchange via
// padded hbuf, halves combined via shfl_xor(32).)
__global__ __launch_bounds__(512, 2) void build_table(
    const float* __restrict__ W1, const float* __restrict__ b1,
    const float* __restrict__ W2, const float* __restrict__ b2,
    const float* __restrict__ W3, const float* __restrict__ b3,
    const float* __restrict__ W4, const float* __restrict__ b4,
    const float* __restrict__ W5, const float* __restrict__ b5,
    float* __restrict__ table)
{
    __shared__ float w[WTOT];
    __shared__ float hbuf[32][65];

    const int tid  = threadIdx.x;
    const int lane = tid & 63;
    const int wave = tid >> 6;
    const int half = lane >> 5;
    const int e    = lane & 31;

    {
        float4*       d2 = (float4*)(w + OFF_W2);
        const float4* s2 = (const float4*)W2;
        d2[tid] = s2[tid];
        float4*       d3 = (float4*)(w + OFF_W3);
        const float4* s3 = (const float4*)W3;
        d3[tid] = s3[tid]; d3[512 + tid] = s3[512 + tid];
        float4*       d4 = (float4*)(w + OFF_W4);
        const float4* s4 = (const float4*)W4;
        d4[tid] = s4[tid];
        if (tid < 32) {
            w[OFF_W1 + tid] = W1[tid];
            w[OFF_B1 + tid] = b1[tid];
            w[OFF_B4 + tid] = b4[tid];
            w[OFF_W5 + tid] = W5[tid];
        }
        if (tid < 64) {
            w[OFF_B2 + tid] = b2[tid];
            w[OFF_B3 + tid] = b3[tid];
        }
        if (tid == 0) w[OFF_B5] = b5[0];
    }
    __syncthreads();

    const int   i = blockIdx.x * 32 + e;
    const float t = 10.0f * (float)i / (float)(TS - 1);

    // L1: 1 -> 32
#pragma unroll
    for (int jj = 0; jj < 4; ++jj) {
        int j = wave * 4 + jj;
        float v = softplus(fmaf(t, w[OFF_W1 + j], w[OFF_B1 + j]));
        if (half == 0) hbuf[e][j] = v;
    }
    __syncthreads();

    // L2: 32 -> 64
    {
        float hr[16];
        const float* hp = &hbuf[e][half * 16];
#pragma unroll
        for (int k = 0; k < 16; ++k) hr[k] = hp[k];
        float acc[8];
#pragma unroll
        for (int jj = 0; jj < 8; ++jj) {
            int j = wave * 8 + jj;
            const float* wp = &w[OFF_W2 + j * 32 + half * 16];
            float a = 0.0f;
#pragma unroll
            for (int k = 0; k < 16; ++k) a = fmaf(hr[k], wp[k], a);
            acc[jj] = a;
        }
        __syncthreads();
#pragma unroll
        for (int jj = 0; jj < 8; ++jj) {
            int j = wave * 8 + jj;
            float s = acc[jj] + __shfl_xor(acc[jj], 32, 64);
            float v = softplus(s + w[OFF_B2 + j]);
            if (half == 0) hbuf[e][j] = v;
        }
    }
    __syncthreads();

    // L3: 64 -> 64
    {
        float hr[32];
        const float* hp = &hbuf[e][half * 32];
#pragma unroll
        for (int k = 0; k < 32; ++k) hr[k] = hp[k];
        float acc[8];
#pragma unroll
        for (int jj = 0; jj < 8; ++jj) {
            int j = wave * 8 + jj;
            const float* wp = &w[OFF_W3 + j * 64 + half * 32];
            float a = 0.0f;
#pragma unroll
            for (int k = 0; k < 32; ++k) a = fmaf(hr[k], wp[k], a);
            acc[jj] = a;
        }
        __syncthreads();
#pragma unroll
        for (int jj = 0; jj < 8; ++jj) {
            int j = wave * 8 + jj;
            float s = acc[jj] + __shfl_xor(acc[jj], 32, 64);
            float v = softplus(s + w[OFF_B3 + j]);
            if (half == 0) hbuf[e][j] = v;
        }
    }
    __syncthreads();

    // L4: 64 -> 32
    {
        float hr[32];
        const float* hp = &hbuf[e][half * 32];
#pragma unroll
        for (int k = 0; k < 32; ++k) hr[k] = hp[k];
        float acc[4];
#pragma unroll
        for (int jj = 0; jj < 4; ++jj) {
            int j = wave * 4 + jj;
            const float* wp = &w[OFF_W4 + j * 64 + half * 32];
            float a = 0.0f;
#pragma unroll
            for (int k = 0; k < 32; ++k) a = fmaf(hr[k], wp[k], a);
            acc[jj] = a;
        }
        __syncthreads();
#pragma unroll
        for (int jj = 0; jj < 4; ++jj) {
            int j = wave * 4 + jj;
            float s = acc[jj] + __shfl_xor(acc[jj], 32, 64);
            float v = softplus(s + w[OFF_B4 + j]);
            if (half == 0) hbuf[e][j] = v;
        }
    }
    __syncthreads();

    // L5: 32 -> 1, +1.0
    if (wave == 0) {
        const float* hp = &hbuf[e][half * 16];
        const float* wp = &w[OFF_W5 + half * 16];
        float a = 0.0f;
#pragma unroll
        for (int k = 0; k < 16; ++k) a = fmaf(hp[k], wp[k], a);
        float s = a + __shfl_xor(a, 32, 64);
        float v = softplus(s + w[OFF_B5]) + 1.0f;
        if (half == 0) table[blockIdx.x * 32 + e] = v;
    }
}

// G-table lookup from padded LDS: entry i lives at (i>>4)*PAD + (i&15)
__device__ __forceinline__ float G_lookup(const float* __restrict__ Gl, float t) {
    const float scale = (float)(TS - 1) / 10.0f;
    float x = t * scale;
    x = fminf(fmaxf(x, 0.0f), (float)(TS - 1));
    int i = (int)x;
    if (i > TS - 2) i = TS - 2;
    float f = x - (float)i;
    float a = Gl[((i)     >> 4) * PAD + ((i)     & 15)];
    float b = Gl[((i + 1) >> 4) * PAD + ((i + 1) & 15)];
    return fmaf(b - a, f, a);
}

// Kernel 2: g[b,j] = G(t[b,j]) - G(t[b,0]) -- NO scan over samples.
// Each block redundantly builds the 4096-entry antiderivative table
// G[i] = h*(P[i] - (dg[0]+dg[i])/2) (uniform trapezoid prefix identity)
// from the L2-resident dg table: 16 dg/thread serial prefix + block scan,
// written to pad-17 LDS (conflict-free: 17 odd -> distinct banks).
// Then a pure streaming map over its 2048 t's. 2048 blocks x 256 threads.
// Kernel-boundary ordering only -- no atomics (R6: agent-scope spin
// caused L2-invalidate storms across XCDs, 91 us).
__global__ __launch_bounds__(256) void g_map(
    const float* __restrict__ t,
    const float* __restrict__ dgtab,
    float* __restrict__ out)
{
    __shared__ float Gl[256 * PAD];   // 17 KB
    __shared__ float woffs[4];

    const int tid  = threadIdx.x;
    const int lane = tid & 63;
    const int wave = tid >> 6;

    // ---- load this thread's 16 consecutive dg entries ----
    float dgv[16];
    {
        const float4* dp = (const float4*)(dgtab + tid * 16);
#pragma unroll
        for (int q = 0; q < 4; ++q) {
            float4 v = dp[q];
            dgv[q * 4 + 0] = v.x; dgv[q * 4 + 1] = v.y;
            dgv[q * 4 + 2] = v.z; dgv[q * 4 + 3] = v.w;
        }
    }
    const float dg0 = dgtab[0];   // block-uniform -> scalar load

    // ---- serial inclusive prefix of 16 entries ----
    float P[16];
    float s = 0.0f;
#pragma unroll
    for (int q = 0; q < 16; ++q) { s += dgv[q]; P[q] = s; }

    // ---- wave scan of per-thread totals ----
    float v = s;
#pragma unroll
    for (int d = 1; d < 64; d <<= 1) {
        float u = __shfl_up(v, d, 64);
        if (lane >= d) v += u;
    }
    if (lane == 63) woffs[wave] = v;
    __syncthreads();
    float excl = v - s;
#pragma unroll
    for (int w = 0; w < 3; ++w)
        excl += (w < wave) ? woffs[w] : 0.0f;

    // ---- write G slice to padded LDS ----
    const float h = 10.0f / (float)(TS - 1);
    float* myG = &Gl[tid * PAD];
#pragma unroll
    for (int q = 0; q < 16; ++q)
        myG[q] = h * (excl + P[q] - 0.5f * (dg0 + dgv[q]));
    __syncthreads();

    // ---- map 2048 t's of this block's chunk ----
    const int row   = blockIdx.x >> 3;          // 0..255
    const int chunk = blockIdx.x & 7;           // 0..7
    const float* tr = t + (size_t)row * NPTS;
    float*       gr = out + (size_t)row * NPTS;
    const int base  = chunk * 2048 + tid * 8;

    const float4* p = (const float4*)(tr + base);
    float4 a4 = p[0], b4 = p[1];
    const float G0 = G_lookup(Gl, tr[0]);       // tr[0] block-uniform

    float4 o0, o1;
    o0.x = G_lookup(Gl, a4.x) - G0;
    o0.y = G_lookup(Gl, a4.y) - G0;
    o0.z = G_lookup(Gl, a4.z) - G0;
    o0.w = G_lookup(Gl, a4.w) - G0;
    o1.x = G_lookup(Gl, b4.x) - G0;
    o1.y = G_lookup(Gl, b4.y) - G0;
    o1.z = G_lookup(Gl, b4.z) - G0;
    o1.w = G_lookup(Gl, b4.w) - G0;

    float4* g4 = (float4*)(gr + base);
    g4[0] = o0;
    g4[1] = o1;
}

extern "C" void kernel_launch(void* const* d_in, const int* in_sizes, int n_in,
                              void* d_out, int out_size, void* d_ws, size_t ws_size,
                              hipStream_t stream)
{
    const float* t  = (const float*)d_in[0];
    const float* W1 = (const float*)d_in[1];
    const float* b1 = (const float*)d_in[2];
    const float* W2 = (const float*)d_in[3];
    const float* b2 = (const float*)d_in[4];
    const float* W3 = (const float*)d_in[5];
    const float* b3 = (const float*)d_in[6];
    const float* W4 = (const float*)d_in[7];
    const float* b4 = (const float*)d_in[8];
    const float* W5 = (const float*)d_in[9];
    const float* b5 = (const float*)d_in[10];
    float* table = (float*)d_ws;    // 16 KB dg table
    float* out   = (float*)d_out;

    build_table<<<TS / 32, 512, 0, stream>>>(W1, b1, W2, b2, W3, b3, W4, b4, W5, b5, table);
    g_map<<<NROWS * 8, 256, 0, stream>>>(t, table, out);
}